// Round 4
// baseline (419.869 us; speedup 1.0000x reference)
//
#include <hip/hip_runtime.h>
#include <cstdint>
#include <cstddef>

#define Bb 2
#define Ss 2048
#define Dd 1024
#define Hh 16

typedef __attribute__((ext_vector_type(8))) short short8;
typedef __attribute__((ext_vector_type(4))) short short4v;
typedef __attribute__((ext_vector_type(4))) float float4v;

__device__ inline short f2bf(float f) {
  unsigned u = __builtin_bit_cast(unsigned, f);
  u = (u + 0x7fffu + ((u >> 16) & 1u)) >> 16;
  return (short)u;
}

__device__ inline void gl_lds16(const void* g, void* l) {
  __builtin_amdgcn_global_load_lds(
      (__attribute__((address_space(1))) void*)(void*)(g),
      (__attribute__((address_space(3))) void*)(l), 16, 0, 0);
}

#define MFMA(a, b, c) __builtin_amdgcn_mfma_f32_16x16x32_bf16((a), (b), (c), 0, 0, 0)

// ---------------- LayerNorm: fp32 in -> bf16 out ----------------
__global__ __launch_bounds__(256) void ln_kernel(const float* __restrict__ x,
                                                 const float* __restrict__ g,
                                                 const float* __restrict__ be,
                                                 short* __restrict__ out) {
  int row = blockIdx.x;
  int tid = threadIdx.x;
  const float4* xr = (const float4*)(x + (size_t)row * Dd);
  float4 v = xr[tid];
  float s = v.x + v.y + v.z + v.w;
  float q = v.x * v.x + v.y * v.y + v.z * v.z + v.w * v.w;
#pragma unroll
  for (int off = 1; off < 64; off <<= 1) {
    s += __shfl_xor(s, off);
    q += __shfl_xor(q, off);
  }
  __shared__ float as_[4], aq_[4];
  int w = tid >> 6;
  if ((tid & 63) == 0) { as_[w] = s; aq_[w] = q; }
  __syncthreads();
  s = as_[0] + as_[1] + as_[2] + as_[3];
  q = aq_[0] + aq_[1] + aq_[2] + aq_[3];
  float mu = s * (1.0f / Dd);
  float var = q * (1.0f / Dd) - mu * mu;
  float rstd = rsqrtf(var + 1e-5f);
  const float4* g4 = (const float4*)g;
  const float4* b4 = (const float4*)be;
  float4 gv = g4[tid], bv = b4[tid];
  short4v o;
  o.x = f2bf((v.x - mu) * rstd * gv.x + bv.x);
  o.y = f2bf((v.y - mu) * rstd * gv.y + bv.y);
  o.z = f2bf((v.z - mu) * rstd * gv.z + bv.z);
  o.w = f2bf((v.w - mu) * rstd * gv.w + bv.w);
  *(short4v*)(out + (size_t)row * Dd + tid * 4) = o;
}

// ---------------- init: dst = src + bias (f32, row-major [4096][1024]) --------
__global__ __launch_bounds__(256) void init_resid_kernel(const float* __restrict__ src,
                                                         const float* __restrict__ bias,
                                                         float* __restrict__ dst) {
  int row = blockIdx.x, tid = threadIdx.x;
  float4 v = ((const float4*)(src + (size_t)row * Dd))[tid];
  float4 bv = ((const float4*)bias)[tid];
  v.x += bv.x; v.y += bv.y; v.z += bv.z; v.w += bv.w;
  ((float4*)(dst + (size_t)row * Dd))[tid] = v;
}

// ---------------- weight transpose fp32[K][N] -> bf16[N][K] ----------------
__global__ __launch_bounds__(256) void wt_kernel(const float* __restrict__ W,
                                                 short* __restrict__ Wt, int K, int N) {
  __shared__ float t[32][33];
  int n0 = blockIdx.x * 32, k0 = blockIdx.y * 32;
  int tx = threadIdx.x & 31, ty = threadIdx.x >> 5;
#pragma unroll
  for (int i = 0; i < 4; i++)
    t[ty + 8 * i][tx] = W[(size_t)(k0 + ty + 8 * i) * N + n0 + tx];
  __syncthreads();
#pragma unroll
  for (int i = 0; i < 4; i++)
    Wt[(size_t)(n0 + ty + 8 * i) * K + k0 + tx] = f2bf(t[tx][ty + 8 * i]);
}

// ---------------- transpose V part of qkv -> Vt[bh][d][s] (bf16) ----------------
__global__ __launch_bounds__(256) void vt_kernel(const short* __restrict__ qkv,
                                                 short* __restrict__ Vt) {
  __shared__ short t[32][34];
  int s0 = blockIdx.x * 32;
  int d0 = blockIdx.y * 32;
  int bh = blockIdx.z;
  int b = bh >> 4, h = bh & 15;
  int tx = threadIdx.x & 31, ty = threadIdx.x >> 5;
#pragma unroll
  for (int i = 0; i < 4; i++)
    t[ty + 8 * i][tx] =
        qkv[(size_t)(b * Ss + s0 + ty + 8 * i) * 3072 + 2048 + h * 64 + d0 + tx];
  __syncthreads();
#pragma unroll
  for (int i = 0; i < 4; i++)
    Vt[(size_t)(bh * 64 + d0 + ty + 8 * i) * Ss + s0 + tx] = t[tx][ty + 8 * i];
}

// ---------------- 128x128 bf16 MFMA GEMM, Bt is [N][K] ----------------
// MODE 0: out bf16 = acc + bias
// MODE 2: out bf16 = gelu(acc + bias)  (tanh-form, hw exp2+rcp)
template <int MODE>
__global__ __launch_bounds__(256) void gemm128(const short* __restrict__ A,
                                               const short* __restrict__ Bt,
                                               const float* __restrict__ bias,
                                               void* __restrict__ outp,
                                               int M, int N, int K) {
  __shared__ __align__(16) short As[128 * 32];
  __shared__ __align__(16) short Bs[128 * 32];
  const int tid = threadIdx.x;
  const int w = tid >> 6, lane = tid & 63;
  const int m0 = blockIdx.y * 128, n0 = blockIdx.x * 128;
  const int ar = lane >> 2;
  const int ac = (lane & 3) * 8;
  const int fr = lane & 15;
  const int fk = (lane >> 4) * 8;
  const int wm = (w >> 1) * 64, wn = (w & 1) * 64;
  float4v acc[4][4] = {};
  const short* Ag = A + (size_t)(m0 + w * 32) * K;
  const short* Bg = Bt + (size_t)(n0 + w * 32) * K;
  short* Asw = As + w * 32 * 32;
  short* Bsw = Bs + w * 32 * 32;
  for (int k0 = 0; k0 < K; k0 += 32) {
    __syncthreads();
    gl_lds16(Ag + (size_t)ar * K + k0 + ac, Asw + ar * 32 + ac);
    gl_lds16(Ag + (size_t)(16 + ar) * K + k0 + ac, Asw + (16 + ar) * 32 + ac);
    gl_lds16(Bg + (size_t)ar * K + k0 + ac, Bsw + ar * 32 + ac);
    gl_lds16(Bg + (size_t)(16 + ar) * K + k0 + ac, Bsw + (16 + ar) * 32 + ac);
    __syncthreads();
    short8 a[4], b[4];
#pragma unroll
    for (int i = 0; i < 4; i++)
      a[i] = *(const short8*)(As + (wm + i * 16 + fr) * 32 + fk);
#pragma unroll
    for (int j = 0; j < 4; j++)
      b[j] = *(const short8*)(Bs + (wn + j * 16 + fr) * 32 + fk);
#pragma unroll
    for (int i = 0; i < 4; i++)
#pragma unroll
      for (int j = 0; j < 4; j++)
        acc[i][j] = MFMA(a[i], b[j], acc[i][j]);
  }
  const int crow = (lane >> 4) * 4;
  const int ccol = lane & 15;
#pragma unroll
  for (int i = 0; i < 4; i++) {
#pragma unroll
    for (int j = 0; j < 4; j++) {
      int col = n0 + wn + j * 16 + ccol;
      float bcol = bias[col];
#pragma unroll
      for (int r = 0; r < 4; r++) {
        int row = m0 + wm + i * 16 + crow + r;
        float v = acc[i][j][r] + bcol;
        if (MODE == 0) {
          ((short*)outp)[(size_t)row * N + col] = f2bf(v);
        } else {
          // gelu tanh-form: 0.5v(1+tanh(0.79788456(v+0.044715 v^3)))
          float y = 0.79788456f * (v + 0.044715f * v * v * v);
          float e = __builtin_amdgcn_exp2f(y * 2.885390082f);  // exp(2y)
          float th = 1.0f - 2.0f * __builtin_amdgcn_rcpf(e + 1.0f);
          v = 0.5f * v * (1.0f + th);
          ((short*)outp)[(size_t)row * N + col] = f2bf(v);
        }
      }
    }
  }
}

// ---------------- split-K GEMM, atomic f32 accumulate into pre-inited out ----
template <int SPLITS>
__global__ __launch_bounds__(256) void gemm128_atomic(const short* __restrict__ A,
                                                      const short* __restrict__ Bt,
                                                      float* __restrict__ outp,
                                                      int M, int N, int K) {
  __shared__ __align__(16) short As[128 * 32];
  __shared__ __align__(16) short Bs[128 * 32];
  const int tid = threadIdx.x;
  const int w = tid >> 6, lane = tid & 63;
  const int m0 = blockIdx.y * 128, n0 = blockIdx.x * 128;
  const int KS = K / SPLITS;
  const int ks = blockIdx.z * KS, ke = ks + KS;
  const int ar = lane >> 2;
  const int ac = (lane & 3) * 8;
  const int fr = lane & 15;
  const int fk = (lane >> 4) * 8;
  const int wm = (w >> 1) * 64, wn = (w & 1) * 64;
  float4v acc[4][4] = {};
  const short* Ag = A + (size_t)(m0 + w * 32) * K;
  const short* Bg = Bt + (size_t)(n0 + w * 32) * K;
  short* Asw = As + w * 32 * 32;
  short* Bsw = Bs + w * 32 * 32;
  for (int k0 = ks; k0 < ke; k0 += 32) {
    __syncthreads();
    gl_lds16(Ag + (size_t)ar * K + k0 + ac, Asw + ar * 32 + ac);
    gl_lds16(Ag + (size_t)(16 + ar) * K + k0 + ac, Asw + (16 + ar) * 32 + ac);
    gl_lds16(Bg + (size_t)ar * K + k0 + ac, Bsw + ar * 32 + ac);
    gl_lds16(Bg + (size_t)(16 + ar) * K + k0 + ac, Bsw + (16 + ar) * 32 + ac);
    __syncthreads();
    short8 a[4], b[4];
#pragma unroll
    for (int i = 0; i < 4; i++)
      a[i] = *(const short8*)(As + (wm + i * 16 + fr) * 32 + fk);
#pragma unroll
    for (int j = 0; j < 4; j++)
      b[j] = *(const short8*)(Bs + (wn + j * 16 + fr) * 32 + fk);
#pragma unroll
    for (int i = 0; i < 4; i++)
#pragma unroll
      for (int j = 0; j < 4; j++)
        acc[i][j] = MFMA(a[i], b[j], acc[i][j]);
  }
  const int crow = (lane >> 4) * 4;
  const int ccol = lane & 15;
#pragma unroll
  for (int i = 0; i < 4; i++) {
#pragma unroll
    for (int j = 0; j < 4; j++) {
      int col = n0 + wn + j * 16 + ccol;
#pragma unroll
      for (int r = 0; r < 4; r++) {
        int row = m0 + wm + i * 16 + crow + r;
        unsafeAtomicAdd(&outp[(size_t)row * N + col], acc[i][j][r]);
      }
    }
  }
}

// ---------------- flash attention, block-cooperative K/V staging ----------------
__global__ __launch_bounds__(256) void flash_kernel(const short* __restrict__ qkv,
                                                    const short* __restrict__ Vt,
                                                    short* __restrict__ att) {
  __shared__ __align__(16) short Ks[4096];      // 64 keys x 64 hd, swizzled
  __shared__ __align__(16) short Vs[4096];      // 64 hd x 64 keys, swizzled
  __shared__ __align__(16) short P[4][16 * 72]; // per-wave P^T, stride 72
  const int w = threadIdx.x >> 6, lane = threadIdx.x & 63;
  const int qb = 31 - (blockIdx.x >> 5);  // heavy blocks first
  const int bh = blockIdx.x & 31;
  const int b = bh >> 4, h = bh & 15;
  const int qbase = qb * 64 + w * 16;
  const int q = lane & 15;
  const int g = lane >> 4;
  const int fk = g * 8;
  short* Pw = &P[w][0];

  const int L0 = w * 64 + lane, L1 = L0 + 256;
  const int r0 = L0 >> 3, c0 = (L0 & 7) ^ (r0 & 7);
  const int r1 = L1 >> 3, c1 = (L1 & 7) ^ (r1 & 7);
  const short* kg0 = qkv + (size_t)(b * Ss + r0) * 3072 + 1024 + h * 64 + c0 * 8;
  const short* kg1 = qkv + (size_t)(b * Ss + r1) * 3072 + 1024 + h * 64 + c1 * 8;
  const short* vg0 = Vt + (size_t)(bh * 64 + r0) * Ss + c0 * 8;
  const short* vg1 = Vt + (size_t)(bh * 64 + r1) * Ss + c1 * 8;

  short8 qf[2];
  {
    const short* qrow = qkv + (size_t)(b * Ss + qbase + q) * 3072 + h * 64;
    qf[0] = *(const short8*)(qrow + fk);
    qf[1] = *(const short8*)(qrow + 32 + fk);
  }
  float4v o[4] = {};
  float l_i = 0.f;
  const float sc = 0.125f * 1.44269504088896f;
  const int nkt = qb + 1;

  for (int kt = 0; kt < nkt; kt++) {
    const int kbase = kt * 64;
    __syncthreads();
    gl_lds16(kg0 + (size_t)kbase * 3072, Ks + L0 * 8);
    gl_lds16(kg1 + (size_t)kbase * 3072, Ks + L1 * 8);
    gl_lds16(vg0 + kbase, Vs + L0 * 8);
    gl_lds16(vg1 + kbase, Vs + L1 * 8);
    __syncthreads();

    short8 kf[4][2], vf[4][2];
#pragma unroll
    for (int t = 0; t < 4; t++) {
      const int row = 16 * t + q;
      const int sw = (g ^ (row & 7)) * 8;
      kf[t][0] = *(const short8*)(Ks + row * 64 + sw);
      kf[t][1] = *(const short8*)(Ks + row * 64 + (sw ^ 32));
      vf[t][0] = *(const short8*)(Vs + row * 64 + sw);
      vf[t][1] = *(const short8*)(Vs + row * 64 + (sw ^ 32));
    }
    float4v s[4] = {};
#pragma unroll
    for (int t = 0; t < 4; t++) {
      s[t] = MFMA(kf[t][0], qf[0], s[t]);
      s[t] = MFMA(kf[t][1], qf[1], s[t]);
    }
    const bool maskt = (kbase + 63 > qbase);
    const int qlim = qbase + q - kbase;
    float p[4][4];
    float rs = 0.f;
#pragma unroll
    for (int t = 0; t < 4; t++) {
#pragma unroll
      for (int r = 0; r < 4; r++) {
        float v = s[t][r] * sc;
        if (maskt && (16 * t + 4 * g + r > qlim)) v = -3.0e38f;
        float e = __builtin_amdgcn_exp2f(v);
        p[t][r] = e;
        rs += e;
      }
    }
    rs += __shfl_xor(rs, 16);
    rs += __shfl_xor(rs, 32);
    l_i += rs;
#pragma unroll
    for (int t = 0; t < 4; t++) {
      unsigned lo = (unsigned)(unsigned short)f2bf(p[t][0]) |
                    ((unsigned)(unsigned short)f2bf(p[t][1]) << 16);
      unsigned hi = (unsigned)(unsigned short)f2bf(p[t][2]) |
                    ((unsigned)(unsigned short)f2bf(p[t][3]) << 16);
      uint2 u; u.x = lo; u.y = hi;
      *(uint2*)(Pw + q * 72 + 16 * t + 4 * g) = u;
    }
    asm volatile("s_waitcnt lgkmcnt(0)" ::: "memory");
    short8 pb0 = *(const short8*)(Pw + q * 72 + fk);
    short8 pb1 = *(const short8*)(Pw + q * 72 + 32 + fk);
#pragma unroll
    for (int t = 0; t < 4; t++) {
      o[t] = MFMA(vf[t][0], pb0, o[t]);
      o[t] = MFMA(vf[t][1], pb1, o[t]);
    }
  }
  const float inv = 1.0f / l_i;
  const int orow = b * Ss + qbase + q;
#pragma unroll
  for (int t = 0; t < 4; t++) {
    short4v ov;
    ov.x = f2bf(o[t][0] * inv);
    ov.y = f2bf(o[t][1] * inv);
    ov.z = f2bf(o[t][2] * inv);
    ov.w = f2bf(o[t][3] * inv);
    *(short4v*)(att + (size_t)orow * Dd + h * 64 + 16 * t + 4 * g) = ov;
  }
}

extern "C" void kernel_launch(void* const* d_in, const int* in_sizes, int n_in,
                              void* d_out, int out_size, void* d_ws, size_t ws_size,
                              hipStream_t stream) {
  const float* x    = (const float*)d_in[0];
  const float* Wqkv = (const float*)d_in[1];
  const float* bqkv = (const float*)d_in[2];
  const float* Wo   = (const float*)d_in[3];
  const float* bo   = (const float*)d_in[4];
  const float* Wfc  = (const float*)d_in[5];
  const float* bfc  = (const float*)d_in[6];
  const float* Wpr  = (const float*)d_in[7];
  const float* bpr  = (const float*)d_in[8];
  const float* g1   = (const float*)d_in[9];
  const float* be1  = (const float*)d_in[10];
  const float* g2   = (const float*)d_in[11];
  const float* be2  = (const float*)d_in[12];

  char* ws = (char*)d_ws;
  size_t off = 0;
  short* h1    = (short*)(ws + off); off += (size_t)4096 * 1024 * 2;
  short* qkv   = (short*)(ws + off); off += (size_t)4096 * 3072 * 2;
  short* Vt    = (short*)(ws + off); off += (size_t)32 * 64 * 2048 * 2;
  short* att   = (short*)(ws + off); off += (size_t)4096 * 1024 * 2;
  float* x1    = (float*)(ws + off); off += (size_t)4096 * 1024 * 4;
  short* h2    = (short*)(ws + off); off += (size_t)4096 * 1024 * 2;
  short* geluo = (short*)(ws + off); off += (size_t)4096 * 4096 * 2;
  short* WtQkv = (short*)(ws + off); off += (size_t)3072 * 1024 * 2;
  short* WtO   = (short*)(ws + off); off += (size_t)1024 * 1024 * 2;
  short* WtFc  = (short*)(ws + off); off += (size_t)4096 * 1024 * 2;
  short* WtPr  = (short*)(ws + off); off += (size_t)1024 * 4096 * 2;

  wt_kernel<<<dim3(3072 / 32, 1024 / 32), 256, 0, stream>>>(Wqkv, WtQkv, 1024, 3072);
  wt_kernel<<<dim3(1024 / 32, 1024 / 32), 256, 0, stream>>>(Wo, WtO, 1024, 1024);
  wt_kernel<<<dim3(4096 / 32, 1024 / 32), 256, 0, stream>>>(Wfc, WtFc, 1024, 4096);
  wt_kernel<<<dim3(1024 / 32, 4096 / 32), 256, 0, stream>>>(Wpr, WtPr, 4096, 1024);

  ln_kernel<<<4096, 256, 0, stream>>>(x, g1, be1, h1);
  gemm128<0><<<dim3(3072 / 128, 4096 / 128), 256, 0, stream>>>(
      h1, WtQkv, bqkv, qkv, 4096, 3072, 1024);
  vt_kernel<<<dim3(64, 2, 32), 256, 0, stream>>>(qkv, Vt);
  flash_kernel<<<1024, 256, 0, stream>>>(qkv, Vt, att);
  // x1 = x + bo, then atomic split-K add of att @ Wo
  init_resid_kernel<<<4096, 256, 0, stream>>>(x, bo, x1);
  gemm128_atomic<2><<<dim3(1024 / 128, 4096 / 128, 2), 256, 0, stream>>>(
      att, WtO, x1, 4096, 1024, 1024);
  ln_kernel<<<4096, 256, 0, stream>>>(x1, g2, be2, h2);
  gemm128<2><<<dim3(4096 / 128, 4096 / 128), 256, 0, stream>>>(
      h2, WtFc, bfc, geluo, 4096, 4096, 1024);
  // out = x1 + bpr, then atomic split-K add of geluo @ Wpr
  init_resid_kernel<<<4096, 256, 0, stream>>>(x1, bpr, (float*)d_out);
  gemm128_atomic<4><<<dim3(1024 / 128, 4096 / 128, 4), 256, 0, stream>>>(
      geluo, WtPr, (float*)d_out, 4096, 1024, 4096);
}

// Round 5
// 376.507 us; speedup vs baseline: 1.1152x; 1.1152x over previous
//
#include <hip/hip_runtime.h>
#include <cstdint>
#include <cstddef>

#define Bb 2
#define Ss 2048
#define Dd 1024
#define Hh 16

typedef __attribute__((ext_vector_type(8))) short short8;
typedef __attribute__((ext_vector_type(4))) short short4v;
typedef __attribute__((ext_vector_type(4))) float float4v;

__device__ inline short f2bf(float f) {
  unsigned u = __builtin_bit_cast(unsigned, f);
  u = (u + 0x7fffu + ((u >> 16) & 1u)) >> 16;
  return (short)u;
}

__device__ inline float bf2f(short s) {
  unsigned u = ((unsigned)(unsigned short)s) << 16;
  return __builtin_bit_cast(float, u);
}

__device__ inline void gl_lds16(const void* g, void* l) {
  __builtin_amdgcn_global_load_lds(
      (__attribute__((address_space(1))) void*)(void*)(g),
      (__attribute__((address_space(3))) void*)(l), 16, 0, 0);
}

#define MFMA(a, b, c) __builtin_amdgcn_mfma_f32_16x16x32_bf16((a), (b), (c), 0, 0, 0)

// ---------------- LayerNorm: fp32 in -> bf16 out ----------------
__global__ __launch_bounds__(256) void ln_kernel(const float* __restrict__ x,
                                                 const float* __restrict__ g,
                                                 const float* __restrict__ be,
                                                 short* __restrict__ out) {
  int row = blockIdx.x;
  int tid = threadIdx.x;
  const float4* xr = (const float4*)(x + (size_t)row * Dd);
  float4 v = xr[tid];
  float s = v.x + v.y + v.z + v.w;
  float q = v.x * v.x + v.y * v.y + v.z * v.z + v.w * v.w;
#pragma unroll
  for (int off = 1; off < 64; off <<= 1) {
    s += __shfl_xor(s, off);
    q += __shfl_xor(q, off);
  }
  __shared__ float as_[4], aq_[4];
  int w = tid >> 6;
  if ((tid & 63) == 0) { as_[w] = s; aq_[w] = q; }
  __syncthreads();
  s = as_[0] + as_[1] + as_[2] + as_[3];
  q = aq_[0] + aq_[1] + aq_[2] + aq_[3];
  float mu = s * (1.0f / Dd);
  float var = q * (1.0f / Dd) - mu * mu;
  float rstd = rsqrtf(var + 1e-5f);
  const float4* g4 = (const float4*)g;
  const float4* b4 = (const float4*)be;
  float4 gv = g4[tid], bv = b4[tid];
  short4v o;
  o.x = f2bf((v.x - mu) * rstd * gv.x + bv.x);
  o.y = f2bf((v.y - mu) * rstd * gv.y + bv.y);
  o.z = f2bf((v.z - mu) * rstd * gv.z + bv.z);
  o.w = f2bf((v.w - mu) * rstd * gv.w + bv.w);
  *(short4v*)(out + (size_t)row * Dd + tid * 4) = o;
}

// ---------------- reduce: dst = src + bias + sum(bf16 partials) ----------------
template <int S>
__global__ __launch_bounds__(256) void reduce_kernel(const float* __restrict__ src,
                                                     const float* __restrict__ bias,
                                                     const short* __restrict__ parts,
                                                     float* __restrict__ dst) {
  int row = blockIdx.x, tid = threadIdx.x;
  size_t base = (size_t)row * Dd + tid * 4;
  float4 v = *(const float4*)(src + base);
  float4 bv = ((const float4*)bias)[tid];
  v.x += bv.x; v.y += bv.y; v.z += bv.z; v.w += bv.w;
#pragma unroll
  for (int s = 0; s < S; s++) {
    short4v p = *(const short4v*)(parts + (size_t)s * 4096 * Dd + base);
    v.x += bf2f(p.x); v.y += bf2f(p.y); v.z += bf2f(p.z); v.w += bf2f(p.w);
  }
  *(float4*)(dst + base) = v;
}

// ---------------- weight transpose fp32[K][N] -> bf16[N][K] ----------------
__global__ __launch_bounds__(256) void wt_kernel(const float* __restrict__ W,
                                                 short* __restrict__ Wt, int K, int N) {
  __shared__ float t[32][33];
  int n0 = blockIdx.x * 32, k0 = blockIdx.y * 32;
  int tx = threadIdx.x & 31, ty = threadIdx.x >> 5;
#pragma unroll
  for (int i = 0; i < 4; i++)
    t[ty + 8 * i][tx] = W[(size_t)(k0 + ty + 8 * i) * N + n0 + tx];
  __syncthreads();
#pragma unroll
  for (int i = 0; i < 4; i++)
    Wt[(size_t)(n0 + ty + 8 * i) * K + k0 + tx] = f2bf(t[tx][ty + 8 * i]);
}

// ---------------- transpose V part of qkv -> Vt[bh][d][s] (bf16) ----------------
__global__ __launch_bounds__(256) void vt_kernel(const short* __restrict__ qkv,
                                                 short* __restrict__ Vt) {
  __shared__ short t[32][34];
  int s0 = blockIdx.x * 32;
  int d0 = blockIdx.y * 32;
  int bh = blockIdx.z;
  int b = bh >> 4, h = bh & 15;
  int tx = threadIdx.x & 31, ty = threadIdx.x >> 5;
#pragma unroll
  for (int i = 0; i < 4; i++)
    t[ty + 8 * i][tx] =
        qkv[(size_t)(b * Ss + s0 + ty + 8 * i) * 3072 + 2048 + h * 64 + d0 + tx];
  __syncthreads();
#pragma unroll
  for (int i = 0; i < 4; i++)
    Vt[(size_t)(bh * 64 + d0 + ty + 8 * i) * Ss + s0 + tx] = t[tx][ty + 8 * i];
}

// ---------------- 128x128 bf16 MFMA GEMM, BK=64, XOR-swizzled LDS ----------------
// Bt is [N][K]. LDS row = 64 shorts (128B); 16B chunk c of row r stored at slot c^(r&7).
// MODE 0: bf16 out = acc + bias
// MODE 2: bf16 out = gelu(acc + bias)  (tanh-form)
// MODE 3: bf16 partial out at outp + z*M*N, no bias
template <int MODE>
__device__ __forceinline__ void gemm_body(const short* __restrict__ A,
                                          const short* __restrict__ Bt,
                                          const float* __restrict__ bias,
                                          void* __restrict__ outp,
                                          int M, int N, int K, int Ksplit) {
  __shared__ __align__(16) short As[128 * 64];
  __shared__ __align__(16) short Bs[128 * 64];
  const int tid = threadIdx.x;
  const int w = tid >> 6, lane = tid & 63;
  const int m0 = blockIdx.y * 128, n0 = blockIdx.x * 128;
  const int ks = blockIdx.z * Ksplit, ke = ks + Ksplit;
  const int sr = lane >> 3;   // staging row-within-8
  const int sc = lane & 7;    // dest slot
  const int gc = sc ^ sr;     // global source chunk (XOR swizzle)
  const int fr = lane & 15;
  const int g = lane >> 4;
  const int wm = (w >> 1) * 64, wn = (w & 1) * 64;
  float4v acc[4][4] = {};
  const short* Ag = A + (size_t)(m0 + w * 32 + sr) * K + gc * 8;
  const short* Bg = Bt + (size_t)(n0 + w * 32 + sr) * K + gc * 8;
  short* Asw = As + (w * 32 + sr) * 64 + sc * 8;
  short* Bsw = Bs + (w * 32 + sr) * 64 + sc * 8;
  for (int k0 = ks; k0 < ke; k0 += 64) {
    __syncthreads();
#pragma unroll
    for (int i = 0; i < 4; i++) {
      gl_lds16(Ag + (size_t)(i * 8) * K + k0, Asw + i * 8 * 64);
      gl_lds16(Bg + (size_t)(i * 8) * K + k0, Bsw + i * 8 * 64);
    }
    __syncthreads();
#pragma unroll
    for (int kh = 0; kh < 2; kh++) {
      short8 a[4], b[4];
#pragma unroll
      for (int i = 0; i < 4; i++) {
        int row = wm + i * 16 + fr;
        int slot = (g + kh * 4) ^ (row & 7);
        a[i] = *(const short8*)(As + row * 64 + slot * 8);
      }
#pragma unroll
      for (int j = 0; j < 4; j++) {
        int row = wn + j * 16 + fr;
        int slot = (g + kh * 4) ^ (row & 7);
        b[j] = *(const short8*)(Bs + row * 64 + slot * 8);
      }
#pragma unroll
      for (int i = 0; i < 4; i++)
#pragma unroll
        for (int j = 0; j < 4; j++)
          acc[i][j] = MFMA(a[i], b[j], acc[i][j]);
    }
  }
  const int crow = g * 4;
  const int ccol = fr;
#pragma unroll
  for (int i = 0; i < 4; i++) {
#pragma unroll
    for (int j = 0; j < 4; j++) {
      int col = n0 + wn + j * 16 + ccol;
      float bcol = (MODE == 3) ? 0.f : bias[col];
#pragma unroll
      for (int r = 0; r < 4; r++) {
        int row = m0 + wm + i * 16 + crow + r;
        float v = acc[i][j][r] + bcol;
        if (MODE == 0) {
          ((short*)outp)[(size_t)row * N + col] = f2bf(v);
        } else if (MODE == 2) {
          float y = 0.79788456f * (v + 0.044715f * v * v * v);
          float e = __builtin_amdgcn_exp2f(y * 2.885390082f);  // exp(2y)
          float th = 1.0f - 2.0f * __builtin_amdgcn_rcpf(e + 1.0f);
          v = 0.5f * v * (1.0f + th);
          ((short*)outp)[(size_t)row * N + col] = f2bf(v);
        } else {
          short* pp = (short*)outp + (size_t)blockIdx.z * M * N;
          pp[(size_t)row * N + col] = f2bf(v);
        }
      }
    }
  }
}

__global__ __launch_bounds__(256) void k_gemm_qkv(const short* A, const short* Bt,
                                                  const float* bias, void* o,
                                                  int M, int N, int K, int Ks) {
  gemm_body<0>(A, Bt, bias, o, M, N, K, Ks);
}
__global__ __launch_bounds__(256) void k_gemm_fc(const short* A, const short* Bt,
                                                 const float* bias, void* o,
                                                 int M, int N, int K, int Ks) {
  gemm_body<2>(A, Bt, bias, o, M, N, K, Ks);
}
__global__ __launch_bounds__(256) void k_gemm_wo(const short* A, const short* Bt,
                                                 const float* bias, void* o,
                                                 int M, int N, int K, int Ks) {
  gemm_body<3>(A, Bt, bias, o, M, N, K, Ks);
}
__global__ __launch_bounds__(256) void k_gemm_pr(const short* A, const short* Bt,
                                                 const float* bias, void* o,
                                                 int M, int N, int K, int Ks) {
  gemm_body<3>(A, Bt, bias, o, M, N, K, Ks);
}

// ---------------- flash attention, block-cooperative K/V staging ----------------
__global__ __launch_bounds__(256) void flash_kernel(const short* __restrict__ qkv,
                                                    const short* __restrict__ Vt,
                                                    short* __restrict__ att) {
  __shared__ __align__(16) short Ks[4096];
  __shared__ __align__(16) short Vs[4096];
  __shared__ __align__(16) short P[4][16 * 72];
  const int w = threadIdx.x >> 6, lane = threadIdx.x & 63;
  const int qb = 31 - (blockIdx.x >> 5);
  const int bh = blockIdx.x & 31;
  const int b = bh >> 4, h = bh & 15;
  const int qbase = qb * 64 + w * 16;
  const int q = lane & 15;
  const int g = lane >> 4;
  const int fk = g * 8;
  short* Pw = &P[w][0];

  const int L0 = w * 64 + lane, L1 = L0 + 256;
  const int r0 = L0 >> 3, c0 = (L0 & 7) ^ (r0 & 7);
  const int r1 = L1 >> 3, c1 = (L1 & 7) ^ (r1 & 7);
  const short* kg0 = qkv + (size_t)(b * Ss + r0) * 3072 + 1024 + h * 64 + c0 * 8;
  const short* kg1 = qkv + (size_t)(b * Ss + r1) * 3072 + 1024 + h * 64 + c1 * 8;
  const short* vg0 = Vt + (size_t)(bh * 64 + r0) * Ss + c0 * 8;
  const short* vg1 = Vt + (size_t)(bh * 64 + r1) * Ss + c1 * 8;

  short8 qf[2];
  {
    const short* qrow = qkv + (size_t)(b * Ss + qbase + q) * 3072 + h * 64;
    qf[0] = *(const short8*)(qrow + fk);
    qf[1] = *(const short8*)(qrow + 32 + fk);
  }
  float4v o[4] = {};
  float l_i = 0.f;
  const float sc = 0.125f * 1.44269504088896f;
  const int nkt = qb + 1;

  for (int kt = 0; kt < nkt; kt++) {
    const int kbase = kt * 64;
    __syncthreads();
    gl_lds16(kg0 + (size_t)kbase * 3072, Ks + L0 * 8);
    gl_lds16(kg1 + (size_t)kbase * 3072, Ks + L1 * 8);
    gl_lds16(vg0 + kbase, Vs + L0 * 8);
    gl_lds16(vg1 + kbase, Vs + L1 * 8);
    __syncthreads();

    short8 kf[4][2], vf[4][2];
#pragma unroll
    for (int t = 0; t < 4; t++) {
      const int row = 16 * t + q;
      const int sw = (g ^ (row & 7)) * 8;
      kf[t][0] = *(const short8*)(Ks + row * 64 + sw);
      kf[t][1] = *(const short8*)(Ks + row * 64 + (sw ^ 32));
      vf[t][0] = *(const short8*)(Vs + row * 64 + sw);
      vf[t][1] = *(const short8*)(Vs + row * 64 + (sw ^ 32));
    }
    float4v s[4] = {};
#pragma unroll
    for (int t = 0; t < 4; t++) {
      s[t] = MFMA(kf[t][0], qf[0], s[t]);
      s[t] = MFMA(kf[t][1], qf[1], s[t]);
    }
    const bool maskt = (kbase + 63 > qbase);
    const int qlim = qbase + q - kbase;
    float p[4][4];
    float rs = 0.f;
#pragma unroll
    for (int t = 0; t < 4; t++) {
#pragma unroll
      for (int r = 0; r < 4; r++) {
        float v = s[t][r] * sc;
        if (maskt && (16 * t + 4 * g + r > qlim)) v = -3.0e38f;
        float e = __builtin_amdgcn_exp2f(v);
        p[t][r] = e;
        rs += e;
      }
    }
    rs += __shfl_xor(rs, 16);
    rs += __shfl_xor(rs, 32);
    l_i += rs;
#pragma unroll
    for (int t = 0; t < 4; t++) {
      unsigned lo = (unsigned)(unsigned short)f2bf(p[t][0]) |
                    ((unsigned)(unsigned short)f2bf(p[t][1]) << 16);
      unsigned hi = (unsigned)(unsigned short)f2bf(p[t][2]) |
                    ((unsigned)(unsigned short)f2bf(p[t][3]) << 16);
      uint2 u; u.x = lo; u.y = hi;
      *(uint2*)(Pw + q * 72 + 16 * t + 4 * g) = u;
    }
    asm volatile("s_waitcnt lgkmcnt(0)" ::: "memory");
    short8 pb0 = *(const short8*)(Pw + q * 72 + fk);
    short8 pb1 = *(const short8*)(Pw + q * 72 + 32 + fk);
#pragma unroll
    for (int t = 0; t < 4; t++) {
      o[t] = MFMA(vf[t][0], pb0, o[t]);
      o[t] = MFMA(vf[t][1], pb1, o[t]);
    }
  }
  const float inv = 1.0f / l_i;
  const int orow = b * Ss + qbase + q;
#pragma unroll
  for (int t = 0; t < 4; t++) {
    short4v ov;
    ov.x = f2bf(o[t][0] * inv);
    ov.y = f2bf(o[t][1] * inv);
    ov.z = f2bf(o[t][2] * inv);
    ov.w = f2bf(o[t][3] * inv);
    *(short4v*)(att + (size_t)orow * Dd + h * 64 + 16 * t + 4 * g) = ov;
  }
}

extern "C" void kernel_launch(void* const* d_in, const int* in_sizes, int n_in,
                              void* d_out, int out_size, void* d_ws, size_t ws_size,
                              hipStream_t stream) {
  const float* x    = (const float*)d_in[0];
  const float* Wqkv = (const float*)d_in[1];
  const float* bqkv = (const float*)d_in[2];
  const float* Wo   = (const float*)d_in[3];
  const float* bo   = (const float*)d_in[4];
  const float* Wfc  = (const float*)d_in[5];
  const float* bfc  = (const float*)d_in[6];
  const float* Wpr  = (const float*)d_in[7];
  const float* bpr  = (const float*)d_in[8];
  const float* g1   = (const float*)d_in[9];
  const float* be1  = (const float*)d_in[10];
  const float* g2   = (const float*)d_in[11];
  const float* be2  = (const float*)d_in[12];

  char* ws = (char*)d_ws;
  const size_t MB = 1024 * 1024;
  // region [0,32MB): h1 [0,8) + qkv [8,32); later partWo [0,16); later partPr [0,32)
  short* h1     = (short*)(ws + 0);
  short* qkvb   = (short*)(ws + 8 * MB);
  short* partWo = (short*)(ws + 0);
  short* partPr = (short*)(ws + 0);
  short* Vt     = (short*)(ws + 32 * MB);
  short* att    = (short*)(ws + 40 * MB);
  float* x1     = (float*)(ws + 48 * MB);
  short* h2     = (short*)(ws + 64 * MB);
  short* geluo  = (short*)(ws + 72 * MB);
  short* WtQkv  = (short*)(ws + 104 * MB);
  short* WtO    = (short*)(ws + 110 * MB);
  short* WtFc   = (short*)(ws + 112 * MB);
  short* WtPr   = (short*)(ws + 120 * MB);

  wt_kernel<<<dim3(3072 / 32, 1024 / 32), 256, 0, stream>>>(Wqkv, WtQkv, 1024, 3072);
  wt_kernel<<<dim3(1024 / 32, 1024 / 32), 256, 0, stream>>>(Wo, WtO, 1024, 1024);
  wt_kernel<<<dim3(4096 / 32, 1024 / 32), 256, 0, stream>>>(Wfc, WtFc, 1024, 4096);
  wt_kernel<<<dim3(1024 / 32, 4096 / 32), 256, 0, stream>>>(Wpr, WtPr, 4096, 1024);

  ln_kernel<<<4096, 256, 0, stream>>>(x, g1, be1, h1);
  k_gemm_qkv<<<dim3(3072 / 128, 4096 / 128), 256, 0, stream>>>(
      h1, WtQkv, bqkv, qkvb, 4096, 3072, 1024, 1024);
  vt_kernel<<<dim3(64, 2, 32), 256, 0, stream>>>(qkvb, Vt);
  flash_kernel<<<1024, 256, 0, stream>>>(qkvb, Vt, att);
  // Wo projection: split-K=2, bf16 partials, then reduce with x + bo -> x1
  k_gemm_wo<<<dim3(1024 / 128, 4096 / 128, 2), 256, 0, stream>>>(
      att, WtO, nullptr, partWo, 4096, 1024, 1024, 512);
  reduce_kernel<2><<<4096, 256, 0, stream>>>(x, bo, partWo, x1);
  ln_kernel<<<4096, 256, 0, stream>>>(x1, g2, be2, h2);
  k_gemm_fc<<<dim3(4096 / 128, 4096 / 128), 256, 0, stream>>>(
      h2, WtFc, bfc, geluo, 4096, 4096, 1024, 1024);
  // pr projection: split-K=4, bf16 partials, then reduce with x1 + bpr -> out
  k_gemm_pr<<<dim3(1024 / 128, 4096 / 128, 4), 256, 0, stream>>>(
      geluo, WtPr, nullptr, partPr, 4096, 1024, 4096, 1024);
  reduce_kernel<4><<<4096, 256, 0, stream>>>(x1, bpr, partPr, (float*)d_out);
}

// Round 6
// 350.175 us; speedup vs baseline: 1.1990x; 1.0752x over previous
//
#include <hip/hip_runtime.h>
#include <cstdint>
#include <cstddef>

#define Bb 2
#define Ss 2048
#define Dd 1024
#define Hh 16

typedef __attribute__((ext_vector_type(8))) short short8;
typedef __attribute__((ext_vector_type(4))) short short4v;
typedef __attribute__((ext_vector_type(4))) float float4v;

__device__ inline short f2bf(float f) {
  unsigned u = __builtin_bit_cast(unsigned, f);
  u = (u + 0x7fffu + ((u >> 16) & 1u)) >> 16;
  return (short)u;
}

__device__ inline float bf2f(short s) {
  unsigned u = ((unsigned)(unsigned short)s) << 16;
  return __builtin_bit_cast(float, u);
}

__device__ inline void gl_lds16(const void* g, void* l) {
  __builtin_amdgcn_global_load_lds(
      (__attribute__((address_space(1))) void*)(void*)(g),
      (__attribute__((address_space(3))) void*)(l), 16, 0, 0);
}

#define MFMA(a, b, c) __builtin_amdgcn_mfma_f32_16x16x32_bf16((a), (b), (c), 0, 0, 0)

// ---------------- LayerNorm: fp32 in -> bf16 out ----------------
__global__ __launch_bounds__(256) void ln_kernel(const float* __restrict__ x,
                                                 const float* __restrict__ g,
                                                 const float* __restrict__ be,
                                                 short* __restrict__ out) {
  int row = blockIdx.x;
  int tid = threadIdx.x;
  const float4* xr = (const float4*)(x + (size_t)row * Dd);
  float4 v = xr[tid];
  float s = v.x + v.y + v.z + v.w;
  float q = v.x * v.x + v.y * v.y + v.z * v.z + v.w * v.w;
#pragma unroll
  for (int off = 1; off < 64; off <<= 1) {
    s += __shfl_xor(s, off);
    q += __shfl_xor(q, off);
  }
  __shared__ float as_[4], aq_[4];
  int w = tid >> 6;
  if ((tid & 63) == 0) { as_[w] = s; aq_[w] = q; }
  __syncthreads();
  s = as_[0] + as_[1] + as_[2] + as_[3];
  q = aq_[0] + aq_[1] + aq_[2] + aq_[3];
  float mu = s * (1.0f / Dd);
  float var = q * (1.0f / Dd) - mu * mu;
  float rstd = rsqrtf(var + 1e-5f);
  const float4* g4 = (const float4*)g;
  const float4* b4 = (const float4*)be;
  float4 gv = g4[tid], bv = b4[tid];
  short4v o;
  o.x = f2bf((v.x - mu) * rstd * gv.x + bv.x);
  o.y = f2bf((v.y - mu) * rstd * gv.y + bv.y);
  o.z = f2bf((v.z - mu) * rstd * gv.z + bv.z);
  o.w = f2bf((v.w - mu) * rstd * gv.w + bv.w);
  *(short4v*)(out + (size_t)row * Dd + tid * 4) = o;
}

// -------- fused: x1 = x + bias + p0 + p1 (write f32), then h2 = LN(x1) bf16 ----
__global__ __launch_bounds__(256) void reduce_ln_kernel(const float* __restrict__ x,
                                                        const float* __restrict__ bias,
                                                        const short* __restrict__ parts,
                                                        const float* __restrict__ g,
                                                        const float* __restrict__ be,
                                                        float* __restrict__ x1,
                                                        short* __restrict__ h2) {
  int row = blockIdx.x, tid = threadIdx.x;
  size_t base = (size_t)row * Dd + tid * 4;
  float4 v = *(const float4*)(x + base);
  float4 bv = ((const float4*)bias)[tid];
  v.x += bv.x; v.y += bv.y; v.z += bv.z; v.w += bv.w;
#pragma unroll
  for (int s = 0; s < 2; s++) {
    short4v p = *(const short4v*)(parts + (size_t)s * 4096 * Dd + base);
    v.x += bf2f(p.x); v.y += bf2f(p.y); v.z += bf2f(p.z); v.w += bf2f(p.w);
  }
  *(float4*)(x1 + base) = v;
  float s = v.x + v.y + v.z + v.w;
  float q = v.x * v.x + v.y * v.y + v.z * v.z + v.w * v.w;
#pragma unroll
  for (int off = 1; off < 64; off <<= 1) {
    s += __shfl_xor(s, off);
    q += __shfl_xor(q, off);
  }
  __shared__ float as_[4], aq_[4];
  int w = tid >> 6;
  if ((tid & 63) == 0) { as_[w] = s; aq_[w] = q; }
  __syncthreads();
  s = as_[0] + as_[1] + as_[2] + as_[3];
  q = aq_[0] + aq_[1] + aq_[2] + aq_[3];
  float mu = s * (1.0f / Dd);
  float var = q * (1.0f / Dd) - mu * mu;
  float rstd = rsqrtf(var + 1e-5f);
  float4 gv = ((const float4*)g)[tid], b2 = ((const float4*)be)[tid];
  short4v o;
  o.x = f2bf((v.x - mu) * rstd * gv.x + b2.x);
  o.y = f2bf((v.y - mu) * rstd * gv.y + b2.y);
  o.z = f2bf((v.z - mu) * rstd * gv.z + b2.z);
  o.w = f2bf((v.w - mu) * rstd * gv.w + b2.w);
  *(short4v*)(h2 + base) = o;
}

// ---------------- final reduce: dst = src + bias + sum(2 bf16 partials) --------
__global__ __launch_bounds__(256) void reduce_kernel(const float* __restrict__ src,
                                                     const float* __restrict__ bias,
                                                     const short* __restrict__ parts,
                                                     float* __restrict__ dst) {
  int row = blockIdx.x, tid = threadIdx.x;
  size_t base = (size_t)row * Dd + tid * 4;
  float4 v = *(const float4*)(src + base);
  float4 bv = ((const float4*)bias)[tid];
  v.x += bv.x; v.y += bv.y; v.z += bv.z; v.w += bv.w;
#pragma unroll
  for (int s = 0; s < 2; s++) {
    short4v p = *(const short4v*)(parts + (size_t)s * 4096 * Dd + base);
    v.x += bf2f(p.x); v.y += bf2f(p.y); v.z += bf2f(p.z); v.w += bf2f(p.w);
  }
  *(float4*)(dst + base) = v;
}

// ------- all-in-one weight transpose fp32[K][N] -> bf16[N][K], 4 matrices -----
__global__ __launch_bounds__(256) void wt_all_kernel(const float* __restrict__ W0,
                                                     short* __restrict__ T0,
                                                     const float* __restrict__ W1,
                                                     short* __restrict__ T1,
                                                     const float* __restrict__ W2,
                                                     short* __restrict__ T2,
                                                     const float* __restrict__ W3,
                                                     short* __restrict__ T3) {
  __shared__ float t[32][33];
  int id = blockIdx.x;
  const float* W; short* Wt; int N, K, tix;
  if (id < 3072)      { W = W0; Wt = T0; N = 3072; K = 1024; tix = id; }
  else if (id < 4096) { W = W1; Wt = T1; N = 1024; K = 1024; tix = id - 3072; }
  else if (id < 8192) { W = W2; Wt = T2; N = 4096; K = 1024; tix = id - 4096; }
  else                { W = W3; Wt = T3; N = 1024; K = 4096; tix = id - 8192; }
  int nx = N / 32;
  int n0 = (tix % nx) * 32, k0 = (tix / nx) * 32;
  int tx = threadIdx.x & 31, ty = threadIdx.x >> 5;
#pragma unroll
  for (int i = 0; i < 4; i++)
    t[ty + 8 * i][tx] = W[(size_t)(k0 + ty + 8 * i) * N + n0 + tx];
  __syncthreads();
#pragma unroll
  for (int i = 0; i < 4; i++)
    Wt[(size_t)(n0 + ty + 8 * i) * K + k0 + tx] = f2bf(t[tx][ty + 8 * i]);
}

// ---------------- transpose V part of qkv -> Vt[bh][d][s] (bf16) ----------------
__global__ __launch_bounds__(256) void vt_kernel(const short* __restrict__ qkv,
                                                 short* __restrict__ Vt) {
  __shared__ short t[32][34];
  int s0 = blockIdx.x * 32;
  int d0 = blockIdx.y * 32;
  int bh = blockIdx.z;
  int b = bh >> 4, h = bh & 15;
  int tx = threadIdx.x & 31, ty = threadIdx.x >> 5;
#pragma unroll
  for (int i = 0; i < 4; i++)
    t[ty + 8 * i][tx] =
        qkv[(size_t)(b * Ss + s0 + ty + 8 * i) * 3072 + 2048 + h * 64 + d0 + tx];
  __syncthreads();
#pragma unroll
  for (int i = 0; i < 4; i++)
    Vt[(size_t)(bh * 64 + d0 + ty + 8 * i) * Ss + s0 + tx] = t[tx][ty + 8 * i];
}

// ---------------- 128x128 bf16 MFMA GEMM, BK=64, XOR-swizzled LDS ----------------
template <int MODE>
__device__ __forceinline__ void gemm_body(const short* __restrict__ A,
                                          const short* __restrict__ Bt,
                                          const float* __restrict__ bias,
                                          void* __restrict__ outp,
                                          int M, int N, int K, int Ksplit) {
  __shared__ __align__(16) short As[128 * 64];
  __shared__ __align__(16) short Bs[128 * 64];
  const int tid = threadIdx.x;
  const int w = tid >> 6, lane = tid & 63;
  const int m0 = blockIdx.y * 128, n0 = blockIdx.x * 128;
  const int ks = blockIdx.z * Ksplit, ke = ks + Ksplit;
  const int sr = lane >> 3;
  const int sc = lane & 7;
  const int gc = sc ^ sr;
  const int fr = lane & 15;
  const int g = lane >> 4;
  const int wm = (w >> 1) * 64, wn = (w & 1) * 64;
  float4v acc[4][4] = {};
  const short* Ag = A + (size_t)(m0 + w * 32 + sr) * K + gc * 8;
  const short* Bg = Bt + (size_t)(n0 + w * 32 + sr) * K + gc * 8;
  short* Asw = As + (w * 32 + sr) * 64 + sc * 8;
  short* Bsw = Bs + (w * 32 + sr) * 64 + sc * 8;
  for (int k0 = ks; k0 < ke; k0 += 64) {
    __syncthreads();
#pragma unroll
    for (int i = 0; i < 4; i++) {
      gl_lds16(Ag + (size_t)(i * 8) * K + k0, Asw + i * 8 * 64);
      gl_lds16(Bg + (size_t)(i * 8) * K + k0, Bsw + i * 8 * 64);
    }
    __syncthreads();
#pragma unroll
    for (int kh = 0; kh < 2; kh++) {
      short8 a[4], b[4];
#pragma unroll
      for (int i = 0; i < 4; i++) {
        int row = wm + i * 16 + fr;
        int slot = (g + kh * 4) ^ (row & 7);
        a[i] = *(const short8*)(As + row * 64 + slot * 8);
      }
#pragma unroll
      for (int j = 0; j < 4; j++) {
        int row = wn + j * 16 + fr;
        int slot = (g + kh * 4) ^ (row & 7);
        b[j] = *(const short8*)(Bs + row * 64 + slot * 8);
      }
#pragma unroll
      for (int i = 0; i < 4; i++)
#pragma unroll
        for (int j = 0; j < 4; j++)
          acc[i][j] = MFMA(a[i], b[j], acc[i][j]);
    }
  }
  const int crow = g * 4;
  const int ccol = fr;
#pragma unroll
  for (int i = 0; i < 4; i++) {
#pragma unroll
    for (int j = 0; j < 4; j++) {
      int col = n0 + wn + j * 16 + ccol;
      float bcol = (MODE == 3) ? 0.f : bias[col];
#pragma unroll
      for (int r = 0; r < 4; r++) {
        int row = m0 + wm + i * 16 + crow + r;
        float v = acc[i][j][r] + bcol;
        if (MODE == 0) {
          ((short*)outp)[(size_t)row * N + col] = f2bf(v);
        } else if (MODE == 2) {
          float y = 0.79788456f * (v + 0.044715f * v * v * v);
          float e = __builtin_amdgcn_exp2f(y * 2.885390082f);  // exp(2y)
          float th = 1.0f - 2.0f * __builtin_amdgcn_rcpf(e + 1.0f);
          v = 0.5f * v * (1.0f + th);
          ((short*)outp)[(size_t)row * N + col] = f2bf(v);
        } else {
          short* pp = (short*)outp + (size_t)blockIdx.z * M * N;
          pp[(size_t)row * N + col] = f2bf(v);
        }
      }
    }
  }
}

__global__ __launch_bounds__(256) void k_gemm_qkv(const short* A, const short* Bt,
                                                  const float* bias, void* o,
                                                  int M, int N, int K, int Ks) {
  gemm_body<0>(A, Bt, bias, o, M, N, K, Ks);
}
__global__ __launch_bounds__(256) void k_gemm_fc(const short* A, const short* Bt,
                                                 const float* bias, void* o,
                                                 int M, int N, int K, int Ks) {
  gemm_body<2>(A, Bt, bias, o, M, N, K, Ks);
}
__global__ __launch_bounds__(256) void k_gemm_wo(const short* A, const short* Bt,
                                                 const float* bias, void* o,
                                                 int M, int N, int K, int Ks) {
  gemm_body<3>(A, Bt, bias, o, M, N, K, Ks);
}
__global__ __launch_bounds__(256) void k_gemm_pr(const short* A, const short* Bt,
                                                 const float* bias, void* o,
                                                 int M, int N, int K, int Ks) {
  gemm_body<3>(A, Bt, bias, o, M, N, K, Ks);
}

// ---------------- flash attention, block-cooperative K/V staging ----------------
__global__ __launch_bounds__(256) void flash_kernel(const short* __restrict__ qkv,
                                                    const short* __restrict__ Vt,
                                                    short* __restrict__ att) {
  __shared__ __align__(16) short Ks[4096];
  __shared__ __align__(16) short Vs[4096];
  __shared__ __align__(16) short P[4][16 * 72];
  const int w = threadIdx.x >> 6, lane = threadIdx.x & 63;
  const int qb = 31 - (blockIdx.x >> 5);
  const int bh = blockIdx.x & 31;
  const int b = bh >> 4, h = bh & 15;
  const int qbase = qb * 64 + w * 16;
  const int q = lane & 15;
  const int g = lane >> 4;
  const int fk = g * 8;
  short* Pw = &P[w][0];

  const int L0 = w * 64 + lane, L1 = L0 + 256;
  const int r0 = L0 >> 3, c0 = (L0 & 7) ^ (r0 & 7);
  const int r1 = L1 >> 3, c1 = (L1 & 7) ^ (r1 & 7);
  const short* kg0 = qkv + (size_t)(b * Ss + r0) * 3072 + 1024 + h * 64 + c0 * 8;
  const short* kg1 = qkv + (size_t)(b * Ss + r1) * 3072 + 1024 + h * 64 + c1 * 8;
  const short* vg0 = Vt + (size_t)(bh * 64 + r0) * Ss + c0 * 8;
  const short* vg1 = Vt + (size_t)(bh * 64 + r1) * Ss + c1 * 8;

  short8 qf[2];
  {
    const short* qrow = qkv + (size_t)(b * Ss + qbase + q) * 3072 + h * 64;
    qf[0] = *(const short8*)(qrow + fk);
    qf[1] = *(const short8*)(qrow + 32 + fk);
  }
  float4v o[4] = {};
  float l_i = 0.f;
  const float sc = 0.125f * 1.44269504088896f;
  const int nkt = qb + 1;

  for (int kt = 0; kt < nkt; kt++) {
    const int kbase = kt * 64;
    __syncthreads();
    gl_lds16(kg0 + (size_t)kbase * 3072, Ks + L0 * 8);
    gl_lds16(kg1 + (size_t)kbase * 3072, Ks + L1 * 8);
    gl_lds16(vg0 + kbase, Vs + L0 * 8);
    gl_lds16(vg1 + kbase, Vs + L1 * 8);
    __syncthreads();

    short8 kf[4][2], vf[4][2];
#pragma unroll
    for (int t = 0; t < 4; t++) {
      const int row = 16 * t + q;
      const int sw = (g ^ (row & 7)) * 8;
      kf[t][0] = *(const short8*)(Ks + row * 64 + sw);
      kf[t][1] = *(const short8*)(Ks + row * 64 + (sw ^ 32));
      vf[t][0] = *(const short8*)(Vs + row * 64 + sw);
      vf[t][1] = *(const short8*)(Vs + row * 64 + (sw ^ 32));
    }
    float4v s[4] = {};
#pragma unroll
    for (int t = 0; t < 4; t++) {
      s[t] = MFMA(kf[t][0], qf[0], s[t]);
      s[t] = MFMA(kf[t][1], qf[1], s[t]);
    }
    const bool maskt = (kbase + 63 > qbase);
    const int qlim = qbase + q - kbase;
    float p[4][4];
    float rs = 0.f;
#pragma unroll
    for (int t = 0; t < 4; t++) {
#pragma unroll
      for (int r = 0; r < 4; r++) {
        float v = s[t][r] * sc;
        if (maskt && (16 * t + 4 * g + r > qlim)) v = -3.0e38f;
        float e = __builtin_amdgcn_exp2f(v);
        p[t][r] = e;
        rs += e;
      }
    }
    rs += __shfl_xor(rs, 16);
    rs += __shfl_xor(rs, 32);
    l_i += rs;
#pragma unroll
    for (int t = 0; t < 4; t++) {
      unsigned lo = (unsigned)(unsigned short)f2bf(p[t][0]) |
                    ((unsigned)(unsigned short)f2bf(p[t][1]) << 16);
      unsigned hi = (unsigned)(unsigned short)f2bf(p[t][2]) |
                    ((unsigned)(unsigned short)f2bf(p[t][3]) << 16);
      uint2 u; u.x = lo; u.y = hi;
      *(uint2*)(Pw + q * 72 + 16 * t + 4 * g) = u;
    }
    asm volatile("s_waitcnt lgkmcnt(0)" ::: "memory");
    short8 pb0 = *(const short8*)(Pw + q * 72 + fk);
    short8 pb1 = *(const short8*)(Pw + q * 72 + 32 + fk);
#pragma unroll
    for (int t = 0; t < 4; t++) {
      o[t] = MFMA(vf[t][0], pb0, o[t]);
      o[t] = MFMA(vf[t][1], pb1, o[t]);
    }
  }
  const float inv = 1.0f / l_i;
  const int orow = b * Ss + qbase + q;
#pragma unroll
  for (int t = 0; t < 4; t++) {
    short4v ov;
    ov.x = f2bf(o[t][0] * inv);
    ov.y = f2bf(o[t][1] * inv);
    ov.z = f2bf(o[t][2] * inv);
    ov.w = f2bf(o[t][3] * inv);
    *(short4v*)(att + (size_t)orow * Dd + h * 64 + 16 * t + 4 * g) = ov;
  }
}

extern "C" void kernel_launch(void* const* d_in, const int* in_sizes, int n_in,
                              void* d_out, int out_size, void* d_ws, size_t ws_size,
                              hipStream_t stream) {
  const float* x    = (const float*)d_in[0];
  const float* Wqkv = (const float*)d_in[1];
  const float* bqkv = (const float*)d_in[2];
  const float* Wo   = (const float*)d_in[3];
  const float* bo   = (const float*)d_in[4];
  const float* Wfc  = (const float*)d_in[5];
  const float* bfc  = (const float*)d_in[6];
  const float* Wpr  = (const float*)d_in[7];
  const float* bpr  = (const float*)d_in[8];
  const float* g1   = (const float*)d_in[9];
  const float* be1  = (const float*)d_in[10];
  const float* g2   = (const float*)d_in[11];
  const float* be2  = (const float*)d_in[12];

  char* ws = (char*)d_ws;
  const size_t MB = 1024 * 1024;
  // region [0,32MB): h1 [0,8) + qkv [8,32); later partWo [0,16); later partPr [0,16)
  short* h1     = (short*)(ws + 0);
  short* qkvb   = (short*)(ws + 8 * MB);
  short* partWo = (short*)(ws + 0);
  short* partPr = (short*)(ws + 0);
  short* Vt     = (short*)(ws + 32 * MB);
  short* att    = (short*)(ws + 40 * MB);
  float* x1     = (float*)(ws + 48 * MB);
  short* h2     = (short*)(ws + 64 * MB);
  short* geluo  = (short*)(ws + 72 * MB);
  short* WtQkv  = (short*)(ws + 104 * MB);
  short* WtO    = (short*)(ws + 110 * MB);
  short* WtFc   = (short*)(ws + 112 * MB);
  short* WtPr   = (short*)(ws + 120 * MB);

  wt_all_kernel<<<12288, 256, 0, stream>>>(Wqkv, WtQkv, Wo, WtO, Wfc, WtFc, Wpr, WtPr);

  ln_kernel<<<4096, 256, 0, stream>>>(x, g1, be1, h1);
  k_gemm_qkv<<<dim3(3072 / 128, 4096 / 128), 256, 0, stream>>>(
      h1, WtQkv, bqkv, qkvb, 4096, 3072, 1024, 1024);
  vt_kernel<<<dim3(64, 2, 32), 256, 0, stream>>>(qkvb, Vt);
  flash_kernel<<<1024, 256, 0, stream>>>(qkvb, Vt, att);
  // Wo projection: split-K=2, bf16 partials
  k_gemm_wo<<<dim3(1024 / 128, 4096 / 128, 2), 256, 0, stream>>>(
      att, WtO, nullptr, partWo, 4096, 1024, 1024, 512);
  // fused: x1 = x + bo + partials; h2 = LN(x1)
  reduce_ln_kernel<<<4096, 256, 0, stream>>>(x, bo, partWo, g2, be2, x1, h2);
  k_gemm_fc<<<dim3(4096 / 128, 4096 / 128), 256, 0, stream>>>(
      h2, WtFc, bfc, geluo, 4096, 4096, 1024, 1024);
  // pr projection: split-K=2, bf16 partials
  k_gemm_pr<<<dim3(1024 / 128, 4096 / 128, 2), 256, 0, stream>>>(
      geluo, WtPr, nullptr, partPr, 4096, 1024, 4096, 2048);
  reduce_kernel<<<4096, 256, 0, stream>>>(x1, bpr, partPr, (float*)d_out);
}